// Round 10
// baseline (333.804 us; speedup 1.0000x reference)
//
#include <hip/hip_runtime.h>
#include <math.h>

#define NROWS 200000
#define DCOLS 512
#define NC 3
#define SGRID 2048
#define NTHREADS (SGRID * 256)        // 524288
#define TOTF4 (NROWS * 128)           // 25,600,000 f4 elements
#define FULLIT 48                     // 48 * NTHREADS = 25,165,824
#define CGRID 2048

typedef float f4 __attribute__((ext_vector_type(4)));

__device__ __forceinline__ float elu1(float x) {
    return x > 0.0f ? x : __expf(x) - 1.0f;
}

__device__ __forceinline__ f4 elu4(f4 w, f4 x) {
    f4 r;
    r.x = elu1(w.x * x.x); r.y = elu1(w.y * x.y);
    r.z = elu1(w.z * x.z); r.w = elu1(w.w * x.w);
    return r;
}

__global__ void zero_sums(float* sums) {
    int t = blockIdx.x * blockDim.x + threadIdx.x;
    if (t < NC * DCOLS) sums[t] = 0.0f;
}

// m13-copy-shaped segment sum: flat unit-stride f4 stream, thread tid
// processes f = tid + k*NTHREADS. Wave base and stride are multiples of 64,
// and a row is 128 f4 -> f>>7 (row) is wave-uniform: label via readfirstlane
// + scalar load + uniform branch. Column slot (tid&127) is loop-invariant.
__global__ __launch_bounds__(256) void segsum_kernel(
        const float* __restrict__ feature, const float* __restrict__ seq,
        const float* __restrict__ weight, const int* __restrict__ labels,
        const int* __restrict__ train, float* __restrict__ sums) {
    const int tid = blockIdx.x * 256 + threadIdx.x;
    const int tr = train[0];
    const f4* __restrict__ src = (const f4*)(tr ? seq : feature);
    const int col = tid & 127;            // f4-column, stable across iters
    f4 w4 = (f4)(0.f);
    if (tr) w4 = ((const f4*)weight)[col];

    f4 a0 = (f4)(0.f), a1 = (f4)(0.f), a2 = (f4)(0.f);

    int f = tid;
    for (int it = 0; it < FULLIT / 4; ++it) {
        int lb[4]; f4 v[4];
        #pragma unroll
        for (int u = 0; u < 4; ++u)
            lb[u] = labels[__builtin_amdgcn_readfirstlane((f + u * NTHREADS) >> 7)];
        #pragma unroll
        for (int u = 0; u < 4; ++u)
            v[u] = src[f + u * NTHREADS];
        #pragma unroll
        for (int u = 0; u < 4; ++u) {
            f4 x = tr ? elu4(w4, v[u]) : v[u];
            if (lb[u] == 0)      a0 += x;
            else if (lb[u] == 1) a1 += x;
            else                 a2 += x;
        }
        f += 4 * NTHREADS;
    }
    // tail: remainder 434176 f4 is wave-aligned (6784 waves) -> uniform guard
    if (f < TOTF4) {
        int lb = labels[__builtin_amdgcn_readfirstlane(f >> 7)];
        f4 x = src[f];
        if (tr) x = elu4(w4, x);
        if (lb == 0)      a0 += x;
        else if (lb == 1) a1 += x;
        else              a2 += x;
    }

    // halves-reduce in LDS, then one atomicAdd per (class,col) per block
    __shared__ float red[NC][128][4];
    const int t = threadIdx.x;
    const int c = t & 127;
    const int h = t >> 7;
    const int c4 = c << 2;
    if (h == 1) {
        *(f4*)red[0][c] = a0;
        *(f4*)red[1][c] = a1;
        *(f4*)red[2][c] = a2;
    }
    __syncthreads();
    if (h == 0) {
        a0 += *(const f4*)red[0][c];
        a1 += *(const f4*)red[1][c];
        a2 += *(const f4*)red[2][c];
        atomicAdd(&sums[0 * DCOLS + c4 + 0], a0.x);
        atomicAdd(&sums[0 * DCOLS + c4 + 1], a0.y);
        atomicAdd(&sums[0 * DCOLS + c4 + 2], a0.z);
        atomicAdd(&sums[0 * DCOLS + c4 + 3], a0.w);
        atomicAdd(&sums[1 * DCOLS + c4 + 0], a1.x);
        atomicAdd(&sums[1 * DCOLS + c4 + 1], a1.y);
        atomicAdd(&sums[1 * DCOLS + c4 + 2], a1.z);
        atomicAdd(&sums[1 * DCOLS + c4 + 3], a1.w);
        atomicAdd(&sums[2 * DCOLS + c4 + 0], a2.x);
        atomicAdd(&sums[2 * DCOLS + c4 + 1], a2.y);
        atomicAdd(&sums[2 * DCOLS + c4 + 2], a2.z);
        atomicAdd(&sums[2 * DCOLS + c4 + 3], a2.w);
    }
}

// ave = sums / (N/2); an[c] = ||ave[c]||. Single block.
__global__ __launch_bounds__(256) void ave_norm_kernel(
        const float* __restrict__ sums, float* __restrict__ ave,
        float* __restrict__ an) {
    __shared__ float red[4];
    const int t = threadIdx.x, lane = t & 63, wv = t >> 6;
    const float inv = 1.0f / (float)(NROWS / 2);
    for (int c = 0; c < NC; ++c) {
        float p = 0.0f;
        for (int j = t; j < DCOLS; j += 256) {
            float v = sums[c * DCOLS + j] * inv;
            ave[c * DCOLS + j] = v;
            p += v * v;
        }
        for (int o = 32; o; o >>= 1) p += __shfl_xor(p, o);
        if (lane == 0) red[wv] = p;
        __syncthreads();
        if (t == 0) an[c] = sqrtf(red[0] + red[1] + red[2] + red[3]);
        __syncthreads();
    }
}

__device__ __forceinline__ void proc4(f4 s, f4 w, f4 a0, f4 a1, f4 a2,
                                      float& rn2, float& d0, float& d1, float& d2) {
    float r;
    r = elu1(w.x * s.x); rn2 = fmaf(r, r, rn2); d0 = fmaf(r, a0.x, d0); d1 = fmaf(r, a1.x, d1); d2 = fmaf(r, a2.x, d2);
    r = elu1(w.y * s.y); rn2 = fmaf(r, r, rn2); d0 = fmaf(r, a0.y, d0); d1 = fmaf(r, a1.y, d1); d2 = fmaf(r, a2.y, d2);
    r = elu1(w.z * s.z); rn2 = fmaf(r, r, rn2); d0 = fmaf(r, a0.z, d0); d1 = fmaf(r, a1.z, d1); d2 = fmaf(r, a2.z, d2);
    r = elu1(w.w * s.w); rn2 = fmaf(r, r, rn2); d0 = fmaf(r, a0.w, d0); d1 = fmaf(r, a1.w, d1); d2 = fmaf(r, a2.w, d2);
}

// One wave per row (proven form). Lane l owns cols [4l,4l+4) and
// [256+4l,256+4l+4): weight + 3 ave rows in registers; butterfly reduce;
// lanes 0..2 write the softmax row.
__global__ __launch_bounds__(256) void cosine_softmax_kernel(
        const float* __restrict__ seq, const float* __restrict__ weight,
        const float* __restrict__ ave, const float* __restrict__ an3,
        float* __restrict__ out) {
    const int lane = threadIdx.x & 63;
    const int wv = threadIdx.x >> 6;
    const int b0 = 4 * lane, b1 = 256 + 4 * lane;
    const f4 w0 = *(const f4*)(weight + b0);
    const f4 w1 = *(const f4*)(weight + b1);
    const f4 a00 = *(const f4*)(ave + 0 * DCOLS + b0);
    const f4 a01 = *(const f4*)(ave + 0 * DCOLS + b1);
    const f4 a10 = *(const f4*)(ave + 1 * DCOLS + b0);
    const f4 a11 = *(const f4*)(ave + 1 * DCOLS + b1);
    const f4 a20 = *(const f4*)(ave + 2 * DCOLS + b0);
    const f4 a21 = *(const f4*)(ave + 2 * DCOLS + b1);
    const float an0 = an3[0], an1 = an3[1], an2 = an3[2];
    for (int row = blockIdx.x * 4 + wv; row < NROWS; row += CGRID * 4) {
        const float* srow = seq + (size_t)row * DCOLS;
        f4 s0 = *(const f4*)(srow + b0);
        f4 s1 = *(const f4*)(srow + b1);
        float rn2 = 0.f, d0 = 0.f, d1 = 0.f, d2 = 0.f;
        proc4(s0, w0, a00, a10, a20, rn2, d0, d1, d2);
        proc4(s1, w1, a01, a11, a21, rn2, d0, d1, d2);
        #pragma unroll
        for (int o = 32; o; o >>= 1) {
            rn2 += __shfl_xor(rn2, o);
            d0  += __shfl_xor(d0, o);
            d1  += __shfl_xor(d1, o);
            d2  += __shfl_xor(d2, o);
        }
        if (lane < 3) {
            const float rn = sqrtf(rn2);
            float s0v = d0 / fmaxf(rn * an0, 1e-8f);
            float s1v = d1 / fmaxf(rn * an1, 1e-8f);
            float s2v = d2 / fmaxf(rn * an2, 1e-8f);
            float m = fmaxf(s0v, fmaxf(s1v, s2v));
            float e0 = __expf(s0v - m), e1 = __expf(s1v - m), e2 = __expf(s2v - m);
            float einv = 1.0f / (e0 + e1 + e2);
            float p = (lane == 0) ? e0 : (lane == 1 ? e1 : e2);
            out[(size_t)row * 3 + lane] = p * einv;
        }
    }
}

extern "C" void kernel_launch(void* const* d_in, const int* in_sizes, int n_in,
                              void* d_out, int out_size, void* d_ws, size_t ws_size,
                              hipStream_t stream) {
    const float* seq     = (const float*)d_in[0];
    const float* feature = (const float*)d_in[1];
    const int*   labels  = (const int*)d_in[2];
    const float* weight  = (const float*)d_in[3];
    const int*   train   = (const int*)d_in[4];
    float* out = (float*)d_out;

    float* sums = (float*)d_ws;           // 1536 floats
    float* ave  = sums + NC * DCOLS;      // 1536 floats
    float* an   = ave + NC * DCOLS;       // 3 floats

    zero_sums<<<6, 256, 0, stream>>>(sums);
    segsum_kernel<<<SGRID, 256, 0, stream>>>(feature, seq, weight, labels, train, sums);
    ave_norm_kernel<<<1, 256, 0, stream>>>(sums, ave, an);
    cosine_softmax_kernel<<<CGRID, 256, 0, stream>>>(seq, weight, ave, an, out);
}

// Round 11
// 323.770 us; speedup vs baseline: 1.0310x; 1.0310x over previous
//
#include <hip/hip_runtime.h>
#include <math.h>

#define NROWS 200000
#define HALFR 100000
#define DCOLS 512
#define NC 3
#define SGRID 2048
#define CGRID 2048

typedef float f4 __attribute__((ext_vector_type(4)));

__device__ __forceinline__ float elu1(float x) {
    return x > 0.0f ? x : __expf(x) - 1.0f;
}

__device__ __forceinline__ f4 elu4(f4 w, f4 x) {
    f4 r;
    r.x = elu1(w.x * x.x); r.y = elu1(w.y * x.y);
    r.z = elu1(w.z * x.z); r.w = elu1(w.w * x.w);
    return r;
}

__global__ void zero_sums(float* sums) {
    int t = blockIdx.x * blockDim.x + threadIdx.x;
    if (t < NC * DCOLS) sums[t] = 0.0f;
}

// Wave-per-row BRANCHLESS segment sum. Identical access pattern to the
// proven cosine kernel (one wave reads a contiguous 2KB row as 2x dwordx4,
// two interleaved row cursors -> 4 independent loads in flight). The 3-way
// label branch is replaced by one-hot mask FMAs into {class0, class1,
// total} accumulators (class2 = total - c0 - c1 at the end), so the inner
// loop is straight-line code the backend can software-pipeline — the
// branch cascade is what serialized loads in all 7 prior variants.
__global__ __launch_bounds__(256) void segsum_kernel(
        const float* __restrict__ feature, const float* __restrict__ seq,
        const float* __restrict__ weight, const int* __restrict__ labels,
        const int* __restrict__ train, float* __restrict__ sums) {
    const int lane = threadIdx.x & 63;
    const int wv = threadIdx.x >> 6;
    const int b0 = 4 * lane, b1 = 256 + 4 * lane;
    const int tr = train[0];
    const float* __restrict__ src = tr ? seq : feature;

    f4 t0 = (f4)(0.f), t1 = (f4)(0.f);     // total
    f4 c00 = (f4)(0.f), c01 = (f4)(0.f);   // class 0
    f4 c10 = (f4)(0.f), c11 = (f4)(0.f);   // class 1

    const int stride = SGRID * 4;
    if (!tr) {
        for (int rA = blockIdx.x * 4 + wv; rA < HALFR; rA += stride) {
            const int rB = rA + HALFR;
            const int la = labels[rA];
            const int lb = labels[rB];
            const float* pA = src + (size_t)rA * DCOLS;
            const float* pB = src + (size_t)rB * DCOLS;
            f4 xA0 = *(const f4*)(pA + b0);
            f4 xA1 = *(const f4*)(pA + b1);
            f4 xB0 = *(const f4*)(pB + b0);
            f4 xB1 = *(const f4*)(pB + b1);
            const f4 mA0 = (f4)(la == 0 ? 1.0f : 0.0f);
            const f4 mA1 = (f4)(la == 1 ? 1.0f : 0.0f);
            const f4 mB0 = (f4)(lb == 0 ? 1.0f : 0.0f);
            const f4 mB1 = (f4)(lb == 1 ? 1.0f : 0.0f);
            t0 += xA0;  t1 += xA1;
            t0 += xB0;  t1 += xB1;
            c00 += mA0 * xA0;  c01 += mA0 * xA1;
            c10 += mA1 * xA0;  c11 += mA1 * xA1;
            c00 += mB0 * xB0;  c01 += mB0 * xB1;
            c10 += mB1 * xB0;  c11 += mB1 * xB1;
        }
    } else {
        f4 wA = *(const f4*)(weight + b0);
        f4 wB = *(const f4*)(weight + b1);
        for (int rA = blockIdx.x * 4 + wv; rA < HALFR; rA += stride) {
            const int rB = rA + HALFR;
            const int la = labels[rA];
            const int lb = labels[rB];
            const float* pA = src + (size_t)rA * DCOLS;
            const float* pB = src + (size_t)rB * DCOLS;
            f4 xA0 = elu4(wA, *(const f4*)(pA + b0));
            f4 xA1 = elu4(wB, *(const f4*)(pA + b1));
            f4 xB0 = elu4(wA, *(const f4*)(pB + b0));
            f4 xB1 = elu4(wB, *(const f4*)(pB + b1));
            const f4 mA0 = (f4)(la == 0 ? 1.0f : 0.0f);
            const f4 mA1 = (f4)(la == 1 ? 1.0f : 0.0f);
            const f4 mB0 = (f4)(lb == 0 ? 1.0f : 0.0f);
            const f4 mB1 = (f4)(lb == 1 ? 1.0f : 0.0f);
            t0 += xA0;  t1 += xA1;
            t0 += xB0;  t1 += xB1;
            c00 += mA0 * xA0;  c01 += mA0 * xA1;
            c10 += mA1 * xA0;  c11 += mA1 * xA1;
            c00 += mB0 * xB0;  c01 += mB0 * xB1;
            c10 += mB1 * xB0;  c11 += mB1 * xB1;
        }
    }

    // class 2 = total - c0 - c1
    f4 c20 = t0 - c00 - c10;
    f4 c21 = t1 - c01 - c11;

    // cross-wave reduce (once): red[wave][class][lane][half]
    __shared__ f4 red[4][NC][64][2];
    red[wv][0][lane][0] = c00; red[wv][0][lane][1] = c01;
    red[wv][1][lane][0] = c10; red[wv][1][lane][1] = c11;
    red[wv][2][lane][0] = c20; red[wv][2][lane][1] = c21;
    __syncthreads();
    if (wv < NC) {   // wave wv reduces class wv
        f4 sA = red[0][wv][lane][0] + red[1][wv][lane][0]
              + red[2][wv][lane][0] + red[3][wv][lane][0];
        f4 sB = red[0][wv][lane][1] + red[1][wv][lane][1]
              + red[2][wv][lane][1] + red[3][wv][lane][1];
        atomicAdd(&sums[wv * DCOLS + b0 + 0], sA.x);
        atomicAdd(&sums[wv * DCOLS + b0 + 1], sA.y);
        atomicAdd(&sums[wv * DCOLS + b0 + 2], sA.z);
        atomicAdd(&sums[wv * DCOLS + b0 + 3], sA.w);
        atomicAdd(&sums[wv * DCOLS + b1 + 0], sB.x);
        atomicAdd(&sums[wv * DCOLS + b1 + 1], sB.y);
        atomicAdd(&sums[wv * DCOLS + b1 + 2], sB.z);
        atomicAdd(&sums[wv * DCOLS + b1 + 3], sB.w);
    }
}

// ave = sums / (N/2); an[c] = ||ave[c]||. Single block.
__global__ __launch_bounds__(256) void ave_norm_kernel(
        const float* __restrict__ sums, float* __restrict__ ave,
        float* __restrict__ an) {
    __shared__ float red[4];
    const int t = threadIdx.x, lane = t & 63, wv = t >> 6;
    const float inv = 1.0f / (float)(NROWS / 2);
    for (int c = 0; c < NC; ++c) {
        float p = 0.0f;
        for (int j = t; j < DCOLS; j += 256) {
            float v = sums[c * DCOLS + j] * inv;
            ave[c * DCOLS + j] = v;
            p += v * v;
        }
        for (int o = 32; o; o >>= 1) p += __shfl_xor(p, o);
        if (lane == 0) red[wv] = p;
        __syncthreads();
        if (t == 0) an[c] = sqrtf(red[0] + red[1] + red[2] + red[3]);
        __syncthreads();
    }
}

__device__ __forceinline__ void proc4(f4 s, f4 w, f4 a0, f4 a1, f4 a2,
                                      float& rn2, float& d0, float& d1, float& d2) {
    float r;
    r = elu1(w.x * s.x); rn2 = fmaf(r, r, rn2); d0 = fmaf(r, a0.x, d0); d1 = fmaf(r, a1.x, d1); d2 = fmaf(r, a2.x, d2);
    r = elu1(w.y * s.y); rn2 = fmaf(r, r, rn2); d0 = fmaf(r, a0.y, d0); d1 = fmaf(r, a1.y, d1); d2 = fmaf(r, a2.y, d2);
    r = elu1(w.z * s.z); rn2 = fmaf(r, r, rn2); d0 = fmaf(r, a0.z, d0); d1 = fmaf(r, a1.z, d1); d2 = fmaf(r, a2.z, d2);
    r = elu1(w.w * s.w); rn2 = fmaf(r, r, rn2); d0 = fmaf(r, a0.w, d0); d1 = fmaf(r, a1.w, d1); d2 = fmaf(r, a2.w, d2);
}

// One wave per row (proven form). Lane l owns cols [4l,4l+4) and
// [256+4l,256+4l+4): weight + 3 ave rows in registers; butterfly reduce;
// lanes 0..2 write the softmax row.
__global__ __launch_bounds__(256) void cosine_softmax_kernel(
        const float* __restrict__ seq, const float* __restrict__ weight,
        const float* __restrict__ ave, const float* __restrict__ an3,
        float* __restrict__ out) {
    const int lane = threadIdx.x & 63;
    const int wv = threadIdx.x >> 6;
    const int b0 = 4 * lane, b1 = 256 + 4 * lane;
    const f4 w0 = *(const f4*)(weight + b0);
    const f4 w1 = *(const f4*)(weight + b1);
    const f4 a00 = *(const f4*)(ave + 0 * DCOLS + b0);
    const f4 a01 = *(const f4*)(ave + 0 * DCOLS + b1);
    const f4 a10 = *(const f4*)(ave + 1 * DCOLS + b0);
    const f4 a11 = *(const f4*)(ave + 1 * DCOLS + b1);
    const f4 a20 = *(const f4*)(ave + 2 * DCOLS + b0);
    const f4 a21 = *(const f4*)(ave + 2 * DCOLS + b1);
    const float an0 = an3[0], an1 = an3[1], an2 = an3[2];
    for (int row = blockIdx.x * 4 + wv; row < NROWS; row += CGRID * 4) {
        const float* srow = seq + (size_t)row * DCOLS;
        f4 s0 = *(const f4*)(srow + b0);
        f4 s1 = *(const f4*)(srow + b1);
        float rn2 = 0.f, d0 = 0.f, d1 = 0.f, d2 = 0.f;
        proc4(s0, w0, a00, a10, a20, rn2, d0, d1, d2);
        proc4(s1, w1, a01, a11, a21, rn2, d0, d1, d2);
        #pragma unroll
        for (int o = 32; o; o >>= 1) {
            rn2 += __shfl_xor(rn2, o);
            d0  += __shfl_xor(d0, o);
            d1  += __shfl_xor(d1, o);
            d2  += __shfl_xor(d2, o);
        }
        if (lane < 3) {
            const float rn = sqrtf(rn2);
            float s0v = d0 / fmaxf(rn * an0, 1e-8f);
            float s1v = d1 / fmaxf(rn * an1, 1e-8f);
            float s2v = d2 / fmaxf(rn * an2, 1e-8f);
            float m = fmaxf(s0v, fmaxf(s1v, s2v));
            float e0 = __expf(s0v - m), e1 = __expf(s1v - m), e2 = __expf(s2v - m);
            float einv = 1.0f / (e0 + e1 + e2);
            float p = (lane == 0) ? e0 : (lane == 1 ? e1 : e2);
            out[(size_t)row * 3 + lane] = p * einv;
        }
    }
}

extern "C" void kernel_launch(void* const* d_in, const int* in_sizes, int n_in,
                              void* d_out, int out_size, void* d_ws, size_t ws_size,
                              hipStream_t stream) {
    const float* seq     = (const float*)d_in[0];
    const float* feature = (const float*)d_in[1];
    const int*   labels  = (const int*)d_in[2];
    const float* weight  = (const float*)d_in[3];
    const int*   train   = (const int*)d_in[4];
    float* out = (float*)d_out;

    float* sums = (float*)d_ws;           // 1536 floats
    float* ave  = sums + NC * DCOLS;      // 1536 floats
    float* an   = ave + NC * DCOLS;       // 3 floats

    zero_sums<<<6, 256, 0, stream>>>(sums);
    segsum_kernel<<<SGRID, 256, 0, stream>>>(feature, seq, weight, labels, train, sums);
    ave_norm_kernel<<<1, 256, 0, stream>>>(sums, ave, an);
    cosine_softmax_kernel<<<CGRID, 256, 0, stream>>>(seq, weight, ave, an, out);
}

// Round 12
// 233.009 us; speedup vs baseline: 1.4326x; 1.3895x over previous
//
#include <hip/hip_runtime.h>
#include <math.h>

#define NROWS 200000
#define DCOLS 512
#define NC 3
#define SGRID 1024
#define WSLOTS (SGRID * 4)       // 4096 wave-slots
#define NFULL 196608             // 48 rows/slot * 4096 slots
#define TAILWS 3392              // wave-slots with one extra row
#define CGRID 2048

typedef float f4 __attribute__((ext_vector_type(4)));

__device__ __forceinline__ float elu1(float x) {
    return x > 0.0f ? x : __expf(x) - 1.0f;
}

__device__ __forceinline__ f4 elu4(f4 w, f4 x) {
    f4 r;
    r.x = elu1(w.x * x.x); r.y = elu1(w.y * x.y);
    r.z = elu1(w.z * x.z); r.w = elu1(w.w * x.w);
    return r;
}

__global__ void zero_sums(float* sums) {
    int t = blockIdx.x * blockDim.x + threadIdx.x;
    if (t < NC * DCOLS) sums[t] = 0.0f;
}

// forced-issue 16B load; "=&v" early-clobber so the backend cannot reuse the
// address regs for the dest, asm ordering keeps all 16 issues back-to-back.
#define GLOAD(dst, ptr) \
    asm volatile("global_load_dwordx4 %0, %1, off" : "=&v"(dst) : "v"(ptr))
#define GLOADO(dst, ptr) \
    asm volatile("global_load_dwordx4 %0, %1, off offset:1024" : "=&v"(dst) : "v"(ptr))

// Wave-per-row segment sum with an ASM-FORCED 16-deep load burst.
// Wave-slot ws = blockIdx.x*4+wv owns rows ws + k*4096 (k=0..47) plus one
// tail row. Per iteration: 8 rows -> 8 addr pairs, 16 global_load_dwordx4
// issued with no intervening waitcnt, single vmcnt(0) drain, then
// branchless one-hot mask FMAs (class2 = total - c0 - c1 at the end).
__global__ __launch_bounds__(256) void segsum_kernel(
        const float* __restrict__ feature, const float* __restrict__ seq,
        const float* __restrict__ weight, const int* __restrict__ labels,
        const int* __restrict__ train, float* __restrict__ sums) {
    const int lane = threadIdx.x & 63;
    const int wv = threadIdx.x >> 6;
    const int ws = blockIdx.x * 4 + wv;
    const int b0 = 4 * lane, b1 = 256 + 4 * lane;
    const int tr = train[0];
    const float* __restrict__ src = tr ? seq : feature;

    f4 t0 = (f4)(0.f), t1 = (f4)(0.f);
    f4 c00 = (f4)(0.f), c01 = (f4)(0.f);
    f4 c10 = (f4)(0.f), c11 = (f4)(0.f);

    if (!tr) {
        #pragma unroll 1
        for (int it = 0; it < 6; ++it) {
            const int base = ws + it * 8 * WSLOTS;
            const float* p0; const float* p1; const float* p2; const float* p3;
            const float* p4; const float* p5; const float* p6; const float* p7;
            int l0, l1, l2, l3, l4, l5, l6, l7;
            l0 = labels[base + 0 * WSLOTS]; p0 = src + (size_t)(base + 0 * WSLOTS) * DCOLS + b0;
            l1 = labels[base + 1 * WSLOTS]; p1 = src + (size_t)(base + 1 * WSLOTS) * DCOLS + b0;
            l2 = labels[base + 2 * WSLOTS]; p2 = src + (size_t)(base + 2 * WSLOTS) * DCOLS + b0;
            l3 = labels[base + 3 * WSLOTS]; p3 = src + (size_t)(base + 3 * WSLOTS) * DCOLS + b0;
            l4 = labels[base + 4 * WSLOTS]; p4 = src + (size_t)(base + 4 * WSLOTS) * DCOLS + b0;
            l5 = labels[base + 5 * WSLOTS]; p5 = src + (size_t)(base + 5 * WSLOTS) * DCOLS + b0;
            l6 = labels[base + 6 * WSLOTS]; p6 = src + (size_t)(base + 6 * WSLOTS) * DCOLS + b0;
            l7 = labels[base + 7 * WSLOTS]; p7 = src + (size_t)(base + 7 * WSLOTS) * DCOLS + b0;
            f4 x0, x1, x2, x3, x4, x5, x6, x7;
            f4 y0, y1, y2, y3, y4, y5, y6, y7;
            GLOAD(x0, p0); GLOADO(y0, p0);
            GLOAD(x1, p1); GLOADO(y1, p1);
            GLOAD(x2, p2); GLOADO(y2, p2);
            GLOAD(x3, p3); GLOADO(y3, p3);
            GLOAD(x4, p4); GLOADO(y4, p4);
            GLOAD(x5, p5); GLOADO(y5, p5);
            GLOAD(x6, p6); GLOADO(y6, p6);
            GLOAD(x7, p7); GLOADO(y7, p7);
            asm volatile("s_waitcnt vmcnt(0)" ::: "memory");
            __builtin_amdgcn_sched_barrier(0);
            #define ACC(lb, xa, ya)                                          \
            {                                                                \
                const f4 m0 = (f4)((lb) == 0 ? 1.0f : 0.0f);                 \
                const f4 m1 = (f4)((lb) == 1 ? 1.0f : 0.0f);                 \
                t0 += xa;  t1 += ya;                                         \
                c00 += m0 * xa;  c01 += m0 * ya;                             \
                c10 += m1 * xa;  c11 += m1 * ya;                             \
            }
            ACC(l0, x0, y0); ACC(l1, x1, y1); ACC(l2, x2, y2); ACC(l3, x3, y3);
            ACC(l4, x4, y4); ACC(l5, x5, y5); ACC(l6, x6, y6); ACC(l7, x7, y7);
        }
        // tail: one extra row for wave-slots < TAILWS
        if (ws < TAILWS) {
            const int r = NFULL + ws;
            const int lb = labels[r];
            const float* p = src + (size_t)r * DCOLS;
            f4 xa = *(const f4*)(p + b0);
            f4 ya = *(const f4*)(p + b1);
            ACC(lb, xa, ya);
        }
    } else {
        const f4 wA = *(const f4*)(weight + b0);
        const f4 wB = *(const f4*)(weight + b1);
        for (int r = ws; r < NROWS; r += WSLOTS) {
            const int lb = labels[r];
            const float* p = src + (size_t)r * DCOLS;
            f4 xa = elu4(wA, *(const f4*)(p + b0));
            f4 ya = elu4(wB, *(const f4*)(p + b1));
            ACC(lb, xa, ya);
        }
    }

    // class 2 = total - c0 - c1
    f4 c20 = t0 - c00 - c10;
    f4 c21 = t1 - c01 - c11;

    // cross-wave reduce (once), then per-block atomics
    __shared__ f4 red[4][NC][64][2];
    red[wv][0][lane][0] = c00; red[wv][0][lane][1] = c01;
    red[wv][1][lane][0] = c10; red[wv][1][lane][1] = c11;
    red[wv][2][lane][0] = c20; red[wv][2][lane][1] = c21;
    __syncthreads();
    if (wv < NC) {
        f4 sA = red[0][wv][lane][0] + red[1][wv][lane][0]
              + red[2][wv][lane][0] + red[3][wv][lane][0];
        f4 sB = red[0][wv][lane][1] + red[1][wv][lane][1]
              + red[2][wv][lane][1] + red[3][wv][lane][1];
        atomicAdd(&sums[wv * DCOLS + b0 + 0], sA.x);
        atomicAdd(&sums[wv * DCOLS + b0 + 1], sA.y);
        atomicAdd(&sums[wv * DCOLS + b0 + 2], sA.z);
        atomicAdd(&sums[wv * DCOLS + b0 + 3], sA.w);
        atomicAdd(&sums[wv * DCOLS + b1 + 0], sB.x);
        atomicAdd(&sums[wv * DCOLS + b1 + 1], sB.y);
        atomicAdd(&sums[wv * DCOLS + b1 + 2], sB.z);
        atomicAdd(&sums[wv * DCOLS + b1 + 3], sB.w);
    }
}

// ave = sums / (N/2); an[c] = ||ave[c]||. Single block.
__global__ __launch_bounds__(256) void ave_norm_kernel(
        const float* __restrict__ sums, float* __restrict__ ave,
        float* __restrict__ an) {
    __shared__ float red[4];
    const int t = threadIdx.x, lane = t & 63, wv = t >> 6;
    const float inv = 1.0f / (float)(NROWS / 2);
    for (int c = 0; c < NC; ++c) {
        float p = 0.0f;
        for (int j = t; j < DCOLS; j += 256) {
            float v = sums[c * DCOLS + j] * inv;
            ave[c * DCOLS + j] = v;
            p += v * v;
        }
        for (int o = 32; o; o >>= 1) p += __shfl_xor(p, o);
        if (lane == 0) red[wv] = p;
        __syncthreads();
        if (t == 0) an[c] = sqrtf(red[0] + red[1] + red[2] + red[3]);
        __syncthreads();
    }
}

__device__ __forceinline__ void proc4(f4 s, f4 w, f4 a0, f4 a1, f4 a2,
                                      float& rn2, float& d0, float& d1, float& d2) {
    float r;
    r = elu1(w.x * s.x); rn2 = fmaf(r, r, rn2); d0 = fmaf(r, a0.x, d0); d1 = fmaf(r, a1.x, d1); d2 = fmaf(r, a2.x, d2);
    r = elu1(w.y * s.y); rn2 = fmaf(r, r, rn2); d0 = fmaf(r, a0.y, d0); d1 = fmaf(r, a1.y, d1); d2 = fmaf(r, a2.y, d2);
    r = elu1(w.z * s.z); rn2 = fmaf(r, r, rn2); d0 = fmaf(r, a0.z, d0); d1 = fmaf(r, a1.z, d1); d2 = fmaf(r, a2.z, d2);
    r = elu1(w.w * s.w); rn2 = fmaf(r, r, rn2); d0 = fmaf(r, a0.w, d0); d1 = fmaf(r, a1.w, d1); d2 = fmaf(r, a2.w, d2);
}

// One wave per row (proven form). Lane l owns cols [4l,4l+4) and
// [256+4l,256+4l+4): weight + 3 ave rows in registers; butterfly reduce;
// lanes 0..2 write the softmax row.
__global__ __launch_bounds__(256) void cosine_softmax_kernel(
        const float* __restrict__ seq, const float* __restrict__ weight,
        const float* __restrict__ ave, const float* __restrict__ an3,
        float* __restrict__ out) {
    const int lane = threadIdx.x & 63;
    const int wv = threadIdx.x >> 6;
    const int b0 = 4 * lane, b1 = 256 + 4 * lane;
    const f4 w0 = *(const f4*)(weight + b0);
    const f4 w1 = *(const f4*)(weight + b1);
    const f4 a00 = *(const f4*)(ave + 0 * DCOLS + b0);
    const f4 a01 = *(const f4*)(ave + 0 * DCOLS + b1);
    const f4 a10 = *(const f4*)(ave + 1 * DCOLS + b0);
    const f4 a11 = *(const f4*)(ave + 1 * DCOLS + b1);
    const f4 a20 = *(const f4*)(ave + 2 * DCOLS + b0);
    const f4 a21 = *(const f4*)(ave + 2 * DCOLS + b1);
    const float an0 = an3[0], an1 = an3[1], an2 = an3[2];
    for (int row = blockIdx.x * 4 + wv; row < NROWS; row += CGRID * 4) {
        const float* srow = seq + (size_t)row * DCOLS;
        f4 s0 = *(const f4*)(srow + b0);
        f4 s1 = *(const f4*)(srow + b1);
        float rn2 = 0.f, d0 = 0.f, d1 = 0.f, d2 = 0.f;
        proc4(s0, w0, a00, a10, a20, rn2, d0, d1, d2);
        proc4(s1, w1, a01, a11, a21, rn2, d0, d1, d2);
        #pragma unroll
        for (int o = 32; o; o >>= 1) {
            rn2 += __shfl_xor(rn2, o);
            d0  += __shfl_xor(d0, o);
            d1  += __shfl_xor(d1, o);
            d2  += __shfl_xor(d2, o);
        }
        if (lane < 3) {
            const float rn = sqrtf(rn2);
            float s0v = d0 / fmaxf(rn * an0, 1e-8f);
            float s1v = d1 / fmaxf(rn * an1, 1e-8f);
            float s2v = d2 / fmaxf(rn * an2, 1e-8f);
            float m = fmaxf(s0v, fmaxf(s1v, s2v));
            float e0 = __expf(s0v - m), e1 = __expf(s1v - m), e2 = __expf(s2v - m);
            float einv = 1.0f / (e0 + e1 + e2);
            float p = (lane == 0) ? e0 : (lane == 1 ? e1 : e2);
            out[(size_t)row * 3 + lane] = p * einv;
        }
    }
}

extern "C" void kernel_launch(void* const* d_in, const int* in_sizes, int n_in,
                              void* d_out, int out_size, void* d_ws, size_t ws_size,
                              hipStream_t stream) {
    const float* seq     = (const float*)d_in[0];
    const float* feature = (const float*)d_in[1];
    const int*   labels  = (const int*)d_in[2];
    const float* weight  = (const float*)d_in[3];
    const int*   train   = (const int*)d_in[4];
    float* out = (float*)d_out;

    float* sums = (float*)d_ws;           // 1536 floats
    float* ave  = sums + NC * DCOLS;      // 1536 floats
    float* an   = ave + NC * DCOLS;       // 3 floats

    zero_sums<<<6, 256, 0, stream>>>(sums);
    segsum_kernel<<<SGRID, 256, 0, stream>>>(feature, seq, weight, labels, train, sums);
    ave_norm_kernel<<<1, 256, 0, stream>>>(sums, ave, an);
    cosine_softmax_kernel<<<CGRID, 256, 0, stream>>>(seq, weight, ave, an, out);
}

// Round 13
// 223.807 us; speedup vs baseline: 1.4915x; 1.0411x over previous
//
#include <hip/hip_runtime.h>
#include <math.h>

#define NROWS 200000
#define DCOLS 512
#define NC 3
#define SGRID 1024
#define RPS (SGRID * 32)   // rows per grid step (32/block: 16 per parity)
#define NFULL 196608       // 6 * RPS
#define TAILB 106          // (NROWS-NFULL)/32 blocks cover tail exactly
#define CGRID 2048

typedef float f4 __attribute__((ext_vector_type(4)));

__device__ __forceinline__ float elu1(float x) {
    return x > 0.0f ? x : __expf(x) - 1.0f;
}

__global__ void zero_sums(float* sums) {
    int t = blockIdx.x * blockDim.x + threadIdx.x;
    if (t < NC * DCOLS) sums[t] = 0.0f;
}

// R5-proven BODY16: 16 independent rows (same parity h) in flight per
// thread, col-sliced float4, wave-uniform label branches.
#define BODY16(base)                                                         \
    {                                                                        \
        int lb[16]; f4 v[16];                                                \
        _Pragma("unroll") for (int j = 0; j < 16; ++j)                       \
            lb[j] = labels[(base) + 2 * j];                                  \
        _Pragma("unroll") for (int j = 0; j < 16; ++j)                       \
            v[j] = *(const f4*)(pbase + (size_t)((base) + 2 * j) * DCOLS);   \
        _Pragma("unroll") for (int j = 0; j < 16; ++j) {                     \
            f4 x = v[j];                                                     \
            if (tr) { x.x = elu1(w4.x * x.x); x.y = elu1(w4.y * x.y);        \
                      x.z = elu1(w4.z * x.z); x.w = elu1(w4.w * x.w); }      \
            if (lb[j] == 0)      a0 += x;                                    \
            else if (lb[j] == 1) a1 += x;                                    \
            else                 a2 += x;                                    \
        }                                                                    \
    }

__global__ __launch_bounds__(256) void segsum_kernel(
        const float* __restrict__ feature, const float* __restrict__ seq,
        const float* __restrict__ weight, const int* __restrict__ labels,
        const int* __restrict__ train, float* __restrict__ sums) {
    const int t = threadIdx.x;
    const int c4 = (t & 127) << 2;   // column base (4 floats)
    const int h  = t >> 7;           // wave-uniform row parity
    const int tr = train[0];
    f4 w4 = (f4)(0.f);
    if (tr) w4 = *(const f4*)(weight + c4);
    const float* __restrict__ src = tr ? seq : feature;
    const float* pbase = src + c4;
    f4 a0 = (f4)(0.f), a1 = (f4)(0.f), a2 = (f4)(0.f);

    for (int base = blockIdx.x * 32 + h; base < NFULL; base += RPS)
        BODY16(base);
    if (blockIdx.x < TAILB)
        BODY16(NFULL + blockIdx.x * 32 + h);

    __shared__ float red[NC][128][4];
    const int c = t & 127;
    if (h == 1) {
        *(f4*)red[0][c] = a0;
        *(f4*)red[1][c] = a1;
        *(f4*)red[2][c] = a2;
    }
    __syncthreads();
    if (h == 0) {
        a0 += *(const f4*)red[0][c];
        a1 += *(const f4*)red[1][c];
        a2 += *(const f4*)red[2][c];
        atomicAdd(&sums[0 * DCOLS + c4 + 0], a0.x);
        atomicAdd(&sums[0 * DCOLS + c4 + 1], a0.y);
        atomicAdd(&sums[0 * DCOLS + c4 + 2], a0.z);
        atomicAdd(&sums[0 * DCOLS + c4 + 3], a0.w);
        atomicAdd(&sums[1 * DCOLS + c4 + 0], a1.x);
        atomicAdd(&sums[1 * DCOLS + c4 + 1], a1.y);
        atomicAdd(&sums[1 * DCOLS + c4 + 2], a1.z);
        atomicAdd(&sums[1 * DCOLS + c4 + 3], a1.w);
        atomicAdd(&sums[2 * DCOLS + c4 + 0], a2.x);
        atomicAdd(&sums[2 * DCOLS + c4 + 1], a2.y);
        atomicAdd(&sums[2 * DCOLS + c4 + 2], a2.z);
        atomicAdd(&sums[2 * DCOLS + c4 + 3], a2.w);
    }
}

__device__ __forceinline__ void proc4(f4 s, f4 w, f4 a0, f4 a1, f4 a2,
                                      float& rn2, float& d0, float& d1, float& d2) {
    float r;
    r = elu1(w.x * s.x); rn2 = fmaf(r, r, rn2); d0 = fmaf(r, a0.x, d0); d1 = fmaf(r, a1.x, d1); d2 = fmaf(r, a2.x, d2);
    r = elu1(w.y * s.y); rn2 = fmaf(r, r, rn2); d0 = fmaf(r, a0.y, d0); d1 = fmaf(r, a1.y, d1); d2 = fmaf(r, a2.y, d2);
    r = elu1(w.z * s.z); rn2 = fmaf(r, r, rn2); d0 = fmaf(r, a0.z, d0); d1 = fmaf(r, a1.z, d1); d2 = fmaf(r, a2.z, d2);
    r = elu1(w.w * s.w); rn2 = fmaf(r, r, rn2); d0 = fmaf(r, a0.w, d0); d1 = fmaf(r, a1.w, d1); d2 = fmaf(r, a2.w, d2);
}

// Cosine+softmax with folded ave/norm derivation (no ave_norm kernel) and
// TWO rows per wave-iteration: 4 independent loads in flight, two
// independent shuffle-reduce chains overlap the serial butterfly latency.
// Prologue: each block reads the 6KB `sums` (L2-resident) and derives the
// per-lane ave fragments and the 3 norms itself.
__global__ __launch_bounds__(256) void cosine_softmax_kernel(
        const float* __restrict__ seq, const float* __restrict__ weight,
        const float* __restrict__ sums, float* __restrict__ out) {
    const int t = threadIdx.x;
    const int lane = t & 63;
    const int wv = t >> 6;
    const int b0 = 4 * lane, b1 = 256 + 4 * lane;
    const float inv = 1.0f / (float)(NROWS / 2);

    // ---- derive norms of the 3 class means (block-local, from sums) ----
    float p0 = 0.f, p1 = 0.f, p2 = 0.f;
    #pragma unroll
    for (int j = 0; j < 2; ++j) {
        const int idx = t + j * 256;
        float s0 = sums[idx], s1 = sums[DCOLS + idx], s2 = sums[2 * DCOLS + idx];
        p0 = fmaf(s0, s0, p0); p1 = fmaf(s1, s1, p1); p2 = fmaf(s2, s2, p2);
    }
    #pragma unroll
    for (int o = 32; o; o >>= 1) {
        p0 += __shfl_xor(p0, o); p1 += __shfl_xor(p1, o); p2 += __shfl_xor(p2, o);
    }
    __shared__ float redn[NC][4];
    if (lane == 0) { redn[0][wv] = p0; redn[1][wv] = p1; redn[2][wv] = p2; }
    __syncthreads();
    const float an0 = inv * sqrtf(redn[0][0] + redn[0][1] + redn[0][2] + redn[0][3]);
    const float an1 = inv * sqrtf(redn[1][0] + redn[1][1] + redn[1][2] + redn[1][3]);
    const float an2 = inv * sqrtf(redn[2][0] + redn[2][1] + redn[2][2] + redn[2][3]);

    // ---- per-lane ave fragments (registers) ----
    const f4 w0 = *(const f4*)(weight + b0);
    const f4 w1 = *(const f4*)(weight + b1);
    const f4 a00 = *(const f4*)(sums + 0 * DCOLS + b0) * inv;
    const f4 a01 = *(const f4*)(sums + 0 * DCOLS + b1) * inv;
    const f4 a10 = *(const f4*)(sums + 1 * DCOLS + b0) * inv;
    const f4 a11 = *(const f4*)(sums + 1 * DCOLS + b1) * inv;
    const f4 a20 = *(const f4*)(sums + 2 * DCOLS + b0) * inv;
    const f4 a21 = *(const f4*)(sums + 2 * DCOLS + b1) * inv;

    // ---- main loop: contiguous row pair per wave-iteration ----
    const int rp = blockIdx.x * 4 + wv;          // wave-slot
    for (int r2 = rp * 2; r2 < NROWS; r2 += CGRID * 8) {
        const float* sA = seq + (size_t)r2 * DCOLS;
        const float* sB = sA + DCOLS;
        f4 xA0 = *(const f4*)(sA + b0);
        f4 xA1 = *(const f4*)(sA + b1);
        f4 xB0 = *(const f4*)(sB + b0);
        f4 xB1 = *(const f4*)(sB + b1);

        float rnA = 0.f, dA0 = 0.f, dA1 = 0.f, dA2 = 0.f;
        float rnB = 0.f, dB0 = 0.f, dB1 = 0.f, dB2 = 0.f;
        proc4(xA0, w0, a00, a10, a20, rnA, dA0, dA1, dA2);
        proc4(xB0, w0, a00, a10, a20, rnB, dB0, dB1, dB2);
        proc4(xA1, w1, a01, a11, a21, rnA, dA0, dA1, dA2);
        proc4(xB1, w1, a01, a11, a21, rnB, dB0, dB1, dB2);

        #pragma unroll
        for (int o = 32; o; o >>= 1) {
            rnA += __shfl_xor(rnA, o); rnB += __shfl_xor(rnB, o);
            dA0 += __shfl_xor(dA0, o); dB0 += __shfl_xor(dB0, o);
            dA1 += __shfl_xor(dA1, o); dB1 += __shfl_xor(dB1, o);
            dA2 += __shfl_xor(dA2, o); dB2 += __shfl_xor(dB2, o);
        }
        if (lane < 3) {
            const float rA = sqrtf(rnA);
            const float rB = sqrtf(rnB);
            float sA0 = __fdividef(dA0, fmaxf(rA * an0, 1e-8f));
            float sA1 = __fdividef(dA1, fmaxf(rA * an1, 1e-8f));
            float sA2 = __fdividef(dA2, fmaxf(rA * an2, 1e-8f));
            float sB0 = __fdividef(dB0, fmaxf(rB * an0, 1e-8f));
            float sB1 = __fdividef(dB1, fmaxf(rB * an1, 1e-8f));
            float sB2 = __fdividef(dB2, fmaxf(rB * an2, 1e-8f));
            float mA = fmaxf(sA0, fmaxf(sA1, sA2));
            float mB = fmaxf(sB0, fmaxf(sB1, sB2));
            float eA0 = __expf(sA0 - mA), eA1 = __expf(sA1 - mA), eA2 = __expf(sA2 - mA);
            float eB0 = __expf(sB0 - mB), eB1 = __expf(sB1 - mB), eB2 = __expf(sB2 - mB);
            float iA = __fdividef(1.0f, eA0 + eA1 + eA2);
            float iB = __fdividef(1.0f, eB0 + eB1 + eB2);
            float pA = (lane == 0) ? eA0 : (lane == 1 ? eA1 : eA2);
            float pB = (lane == 0) ? eB0 : (lane == 1 ? eB1 : eB2);
            out[(size_t)r2 * 3 + lane] = pA * iA;
            out[(size_t)(r2 + 1) * 3 + lane] = pB * iB;
        }
    }
}

extern "C" void kernel_launch(void* const* d_in, const int* in_sizes, int n_in,
                              void* d_out, int out_size, void* d_ws, size_t ws_size,
                              hipStream_t stream) {
    const float* seq     = (const float*)d_in[0];
    const float* feature = (const float*)d_in[1];
    const int*   labels  = (const int*)d_in[2];
    const float* weight  = (const float*)d_in[3];
    const int*   train   = (const int*)d_in[4];
    float* out = (float*)d_out;

    float* sums = (float*)d_ws;           // 1536 floats

    zero_sums<<<6, 256, 0, stream>>>(sums);
    segsum_kernel<<<SGRID, 256, 0, stream>>>(feature, seq, weight, labels, train, sums);
    cosine_softmax_kernel<<<CGRID, 256, 0, stream>>>(seq, weight, sums, out);
}